// Round 1
// baseline (2168.032 us; speedup 1.0000x reference)
//
#include <hip/hip_runtime.h>
#include <math.h>

#define Hn   256
#define En   128
#define Vn   256
#define TPn  32
#define BTn  2048
#define NSEQ 8
#define NWG  (BTn / NSEQ)   // 256 workgroups

// ---------------- precompute kernels ----------------

// P[v][u] = float4 over gates {i,f,g,o}: emb[v] @ Wih[gate_row]^T + bih + bhh
// grid: 256 blocks (v), 256 threads (u)
__global__ void make_ptab(float4* __restrict__ Pp, const float* __restrict__ emb,
                          const float* __restrict__ Wih, const float* __restrict__ bih,
                          const float* __restrict__ bhh) {
    int v = blockIdx.x, u = threadIdx.x;
    __shared__ __align__(16) float es[En];
    if (u < En) es[u] = emb[v * En + u];
    __syncthreads();
    float a0 = bih[u]       + bhh[u];
    float a1 = bih[256 + u] + bhh[256 + u];
    float a2 = bih[512 + u] + bhh[512 + u];
    float a3 = bih[768 + u] + bhh[768 + u];
    for (int e = 0; e < En; ++e) {
        float x = es[e];
        a0 = fmaf(x, Wih[(u)       * En + e], a0);
        a1 = fmaf(x, Wih[(256 + u) * En + e], a1);
        a2 = fmaf(x, Wih[(512 + u) * En + e], a2);
        a3 = fmaf(x, Wih[(768 + u) * En + e], a3);
    }
    Pp[v * 256 + u] = make_float4(a0, a1, a2, a3);
}

// Wp[e*256+u] = float4{Whh[u][e], Whh[256+u][e], Whh[512+u][e], Whh[768+u][e]}
// grid: 256 blocks, 256 threads
__global__ void pack_whh(float4* __restrict__ Wp, const float* __restrict__ Whh) {
    int i = blockIdx.x * 256 + threadIdx.x;
    int e = i >> 8, u = i & 255;
    Wp[i] = make_float4(Whh[u * Hn + e], Whh[(256 + u) * Hn + e],
                        Whh[(512 + u) * Hn + e], Whh[(768 + u) * Hn + e]);
}

// Fp[u4*256+v] = float4{fc_W[v][4u4 .. 4u4+3]}   grid: 64 blocks, 256 threads
__global__ void pack_fc(float4* __restrict__ Fp, const float* __restrict__ fcW) {
    int i = blockIdx.x * 256 + threadIdx.x;
    int u4 = i >> 8, v = i & 255;
    Fp[i] = make_float4(fcW[v * Hn + 4 * u4], fcW[v * Hn + 4 * u4 + 1],
                        fcW[v * Hn + 4 * u4 + 2], fcW[v * Hn + 4 * u4 + 3]);
}

// ---------------- LSTM step helpers ----------------

__device__ __forceinline__ float sigf(float x) { return 1.0f / (1.0f + expf(-x)); }

// ---------------- encoder ----------------
// 256 WGs x 256 threads, 8 seqs per WG, thread u = hidden unit u (all 4 gates)
__global__ __launch_bounds__(256, 1) void enc_kernel(
    const float4* __restrict__ Pp, const float4* __restrict__ Wp,
    const int* __restrict__ phon, const int* __restrict__ lens,
    float* __restrict__ h0dec) {
    const int u = threadIdx.x, wg = blockIdx.x;
    __shared__ __align__(16) float hs[NSEQ][Hn];
    float c[NSEQ];
    int len[NSEQ];
#pragma unroll
    for (int s = 0; s < NSEQ; ++s) {
        hs[s][u] = 0.0f;
        c[s] = 0.0f;
        len[s] = lens[wg * NSEQ + s];
    }
    __syncthreads();

    const float4* h4 = reinterpret_cast<const float4*>(&hs[0][0]);  // [s*64 + e4]

    for (int t = 0; t < TPn; ++t) {
        float ai[NSEQ], af[NSEQ], ag[NSEQ], ao[NSEQ];
#pragma unroll
        for (int s = 0; s < NSEQ; ++s) {
            int tok = phon[(wg * NSEQ + s) * TPn + t];
            float4 p = Pp[tok * 256 + u];
            ai[s] = p.x; af[s] = p.y; ag[s] = p.z; ao[s] = p.w;
        }
        for (int e4 = 0; e4 < 64; ++e4) {
            float4 w0 = Wp[(4 * e4 + 0) * 256 + u];
            float4 w1 = Wp[(4 * e4 + 1) * 256 + u];
            float4 w2 = Wp[(4 * e4 + 2) * 256 + u];
            float4 w3 = Wp[(4 * e4 + 3) * 256 + u];
#pragma unroll
            for (int s = 0; s < NSEQ; ++s) {
                float4 hv = h4[s * 64 + e4];
                ai[s] = fmaf(w0.x, hv.x, fmaf(w1.x, hv.y, fmaf(w2.x, hv.z, fmaf(w3.x, hv.w, ai[s]))));
                af[s] = fmaf(w0.y, hv.x, fmaf(w1.y, hv.y, fmaf(w2.y, hv.z, fmaf(w3.y, hv.w, af[s]))));
                ag[s] = fmaf(w0.z, hv.x, fmaf(w1.z, hv.y, fmaf(w2.z, hv.z, fmaf(w3.z, hv.w, ag[s]))));
                ao[s] = fmaf(w0.w, hv.x, fmaf(w1.w, hv.y, fmaf(w2.w, hv.z, fmaf(w3.w, hv.w, ao[s]))));
            }
        }
        __syncthreads();   // all reads of hs done
#pragma unroll
        for (int s = 0; s < NSEQ; ++s) {
            float gi = sigf(ai[s]);
            float gf = sigf(af[s]);
            float gg = tanhf(ag[s]);
            float go = sigf(ao[s]);
            float cn = fmaf(gf, c[s], gi * gg);
            float hn = go * tanhf(cn);
            c[s] = cn;
            hs[s][u] = hn;
            if (t == len[s] - 1) h0dec[(wg * NSEQ + s) * Hn + u] = hn;
        }
        __syncthreads();   // new hs visible
    }
}

// ---------------- decoder ----------------
__global__ __launch_bounds__(256, 1) void dec_kernel(
    const float4* __restrict__ Pp, const float4* __restrict__ Wp,
    const float4* __restrict__ Fp, const float* __restrict__ fcb,
    const float* __restrict__ h0dec, const int* __restrict__ sosp,
    float* __restrict__ out) {
    const int u = threadIdx.x, wg = blockIdx.x;
    __shared__ __align__(16) float hs[NSEQ][Hn];
    __shared__ int toks[NSEQ];
    __shared__ unsigned long long wmax[4][NSEQ];
    float c[NSEQ];
#pragma unroll
    for (int s = 0; s < NSEQ; ++s) {
        hs[s][u] = h0dec[(wg * NSEQ + s) * Hn + u];
        c[s] = 0.0f;
    }
    if (u < NSEQ) toks[u] = sosp[0];
    const float bv = fcb[u];   // thread u <-> vocab v=u in the fc phase
    __syncthreads();

    const float4* h4 = reinterpret_cast<const float4*>(&hs[0][0]);

    for (int t = 0; t < TPn; ++t) {
        float ai[NSEQ], af[NSEQ], ag[NSEQ], ao[NSEQ];
#pragma unroll
        for (int s = 0; s < NSEQ; ++s) {
            float4 p = Pp[toks[s] * 256 + u];
            ai[s] = p.x; af[s] = p.y; ag[s] = p.z; ao[s] = p.w;
        }
        for (int e4 = 0; e4 < 64; ++e4) {
            float4 w0 = Wp[(4 * e4 + 0) * 256 + u];
            float4 w1 = Wp[(4 * e4 + 1) * 256 + u];
            float4 w2 = Wp[(4 * e4 + 2) * 256 + u];
            float4 w3 = Wp[(4 * e4 + 3) * 256 + u];
#pragma unroll
            for (int s = 0; s < NSEQ; ++s) {
                float4 hv = h4[s * 64 + e4];
                ai[s] = fmaf(w0.x, hv.x, fmaf(w1.x, hv.y, fmaf(w2.x, hv.z, fmaf(w3.x, hv.w, ai[s]))));
                af[s] = fmaf(w0.y, hv.x, fmaf(w1.y, hv.y, fmaf(w2.y, hv.z, fmaf(w3.y, hv.w, af[s]))));
                ag[s] = fmaf(w0.z, hv.x, fmaf(w1.z, hv.y, fmaf(w2.z, hv.z, fmaf(w3.z, hv.w, ag[s]))));
                ao[s] = fmaf(w0.w, hv.x, fmaf(w1.w, hv.y, fmaf(w2.w, hv.z, fmaf(w3.w, hv.w, ao[s]))));
            }
        }
        __syncthreads();   // all reads of hs done
#pragma unroll
        for (int s = 0; s < NSEQ; ++s) {
            float gi = sigf(ai[s]);
            float gf = sigf(af[s]);
            float gg = tanhf(ag[s]);
            float go = sigf(ao[s]);
            float cn = fmaf(gf, c[s], gi * gg);
            float hn = go * tanhf(cn);
            c[s] = cn;
            hs[s][u] = hn;
        }
        __syncthreads();   // new hs visible

        // fc: scores[s][v=u] = hs[s] . fc_W[v] + fc_b[v]
        float sc[NSEQ];
#pragma unroll
        for (int s = 0; s < NSEQ; ++s) sc[s] = bv;
        for (int u4 = 0; u4 < 64; ++u4) {
            float4 w = Fp[u4 * 256 + u];
#pragma unroll
            for (int s = 0; s < NSEQ; ++s) {
                float4 hv = h4[s * 64 + u4];
                sc[s] = fmaf(w.x, hv.x, fmaf(w.y, hv.y, fmaf(w.z, hv.z, fmaf(w.w, hv.w, sc[s]))));
            }
        }
        const int sg = wg * NSEQ;
#pragma unroll
        for (int s = 0; s < NSEQ; ++s) {
            out[((long)(sg + s) * TPn + t) * Vn + u] = sc[s];
        }
        // argmax over v (first-index tie-break) via order-preserving key
#pragma unroll
        for (int s = 0; s < NSEQ; ++s) {
            unsigned int fb = __float_as_uint(sc[s]);
            fb = (fb & 0x80000000u) ? ~fb : (fb | 0x80000000u);
            unsigned long long key =
                ((unsigned long long)fb << 32) | (unsigned int)(Vn - 1 - u);
            for (int off = 32; off > 0; off >>= 1) {
                unsigned long long o = __shfl_xor(key, off, 64);
                if (o > key) key = o;
            }
            if ((u & 63) == 0) wmax[u >> 6][s] = key;
        }
        __syncthreads();
        if (u < NSEQ) {
            unsigned long long k = wmax[0][u];
#pragma unroll
            for (int w = 1; w < 4; ++w)
                if (wmax[w][u] > k) k = wmax[w][u];
            toks[u] = Vn - 1 - (int)(k & 0xffffffffu);
        }
        __syncthreads();
    }
}

// ---------------- launch ----------------
extern "C" void kernel_launch(void* const* d_in, const int* in_sizes, int n_in,
                              void* d_out, int out_size, void* d_ws, size_t ws_size,
                              hipStream_t stream) {
    const int*   phon = (const int*)d_in[0];
    const int*   lens = (const int*)d_in[1];
    const float* emb  = (const float*)d_in[2];
    const float* eWih = (const float*)d_in[3];
    const float* eWhh = (const float*)d_in[4];
    const float* ebih = (const float*)d_in[5];
    const float* ebhh = (const float*)d_in[6];
    const float* dWih = (const float*)d_in[7];
    const float* dWhh = (const float*)d_in[8];
    const float* dbih = (const float*)d_in[9];
    const float* dbhh = (const float*)d_in[10];
    const float* fcW  = (const float*)d_in[11];
    const float* fcb  = (const float*)d_in[12];
    const int*   sos  = (const int*)d_in[13];
    float* out = (float*)d_out;

    float4* Pp_e = (float4*)d_ws;           // 65536 float4 = 1 MB
    float4* Pp_d = Pp_e + 65536;            // 1 MB
    float4* Wp_e = Pp_d + 65536;            // 1 MB
    float4* Wp_d = Wp_e + 65536;            // 1 MB
    float4* Fp   = Wp_d + 65536;            // 16384 float4 = 256 KB
    float*  h0d  = (float*)(Fp + 16384);    // 2048*256 floats = 2 MB

    make_ptab<<<256, 256, 0, stream>>>(Pp_e, emb, eWih, ebih, ebhh);
    make_ptab<<<256, 256, 0, stream>>>(Pp_d, emb, dWih, dbih, dbhh);
    pack_whh<<<256, 256, 0, stream>>>(Wp_e, eWhh);
    pack_whh<<<256, 256, 0, stream>>>(Wp_d, dWhh);
    pack_fc<<<64, 256, 0, stream>>>(Fp, fcW);
    enc_kernel<<<NWG, 256, 0, stream>>>(Pp_e, Wp_e, phon, lens, h0d);
    dec_kernel<<<NWG, 256, 0, stream>>>(Pp_d, Wp_d, Fp, fcb, h0d, sos, out);
}

// Round 2
// 1784.575 us; speedup vs baseline: 1.2149x; 1.2149x over previous
//
#include <hip/hip_runtime.h>
#include <math.h>

#define Hn   256
#define En   128
#define Vn   256
#define TPn  32
#define BTn  2048
#define NSEQ 8
#define NWG  (BTn / NSEQ)   // 256 workgroups
#define NT   1024           // threads per WG: 16 waves/CU

// ---------------- precompute kernels ----------------

// Pt[v*1024 + r] = emb[v] @ Wih[r]^T + bih[r] + bhh[r],  r = g*256+u in [0,1024)
// grid: 256 blocks (v), 1024 threads (r)
__global__ void make_ptab(float* __restrict__ Pt, const float* __restrict__ emb,
                          const float* __restrict__ Wih, const float* __restrict__ bih,
                          const float* __restrict__ bhh) {
    int v = blockIdx.x, r = threadIdx.x;
    __shared__ __align__(16) float es[En];
    if (r < En) es[r] = emb[v * En + r];
    __syncthreads();
    float a = bih[r] + bhh[r];
    const float4* w4 = reinterpret_cast<const float4*>(Wih + r * En);
    const float4* e4 = reinterpret_cast<const float4*>(es);
    for (int k = 0; k < En / 4; ++k) {
        float4 w = w4[k], x = e4[k];
        a = fmaf(w.x, x.x, fmaf(w.y, x.y, fmaf(w.z, x.z, fmaf(w.w, x.w, a))));
    }
    Pt[v * 1024 + r] = a;
}

// Wq[e4*1024 + r] = float4{ Whh[r][4e4 .. 4e4+3] }   (65536 entries)
__global__ void pack_whh(float4* __restrict__ Wq, const float* __restrict__ Whh) {
    int i = blockIdx.x * 256 + threadIdx.x;
    int e4 = i >> 10, r = i & 1023;
    Wq[i] = reinterpret_cast<const float4*>(Whh)[r * 64 + e4];
}

// Fq[e4*256 + v] = float4{ fc_W[v][4e4 .. 4e4+3] }   (16384 entries)
__global__ void pack_fc(float4* __restrict__ Fq, const float* __restrict__ fcW) {
    int i = blockIdx.x * 256 + threadIdx.x;
    int e4 = i >> 8, v = i & 255;
    Fq[i] = reinterpret_cast<const float4*>(fcW)[v * 64 + e4];
}

__device__ __forceinline__ float sigf(float x) { return 1.0f / (1.0f + expf(-x)); }

// ---------------- encoder ----------------
// 256 WGs x 1024 threads. Matmul phase: thread=(g,u) computes gate g, unit u for
// all 8 seqs. Update phase: thread=(q,u) updates seqs {2q,2q+1} unit u.
__global__ __launch_bounds__(NT, 4) void enc_kernel(
    const float* __restrict__ Pt, const float4* __restrict__ Wq,
    const int* __restrict__ phon, const int* __restrict__ lens,
    float* __restrict__ h0dec) {
    const int tid = threadIdx.x, wg = blockIdx.x;
    const int u = tid & 255;
    const int q = tid >> 8;       // gate index in matmul phase, seq-group in update
    __shared__ __align__(16) float hs[NSEQ][Hn];        // 8 KB
    __shared__ __align__(16) float aex[4][NSEQ][Hn];    // 32 KB gate exchange
    __shared__ int mxs;

    const int s0 = 2 * q, s1 = 2 * q + 1;
    hs[s0][u] = 0.0f;
    hs[s1][u] = 0.0f;
    float c0 = 0.0f, c1 = 0.0f;
    const int len0 = lens[wg * NSEQ + s0];
    const int len1 = lens[wg * NSEQ + s1];
    if (tid == 0) {
        int m = 0;
        for (int s = 0; s < NSEQ; ++s) {
            int l = lens[wg * NSEQ + s];
            m = l > m ? l : m;
        }
        mxs = m;
    }
    __syncthreads();
    const int mx = mxs;

    const float4* h4 = reinterpret_cast<const float4*>(&hs[0][0]);  // [s*64 + e4]

    for (int t = 0; t < mx; ++t) {
        float acc[NSEQ];
#pragma unroll
        for (int s = 0; s < NSEQ; ++s) {
            int tk = phon[(wg * NSEQ + s) * TPn + t];
            acc[s] = Pt[tk * 1024 + tid];
        }
#pragma unroll 8
        for (int e4 = 0; e4 < 64; ++e4) {
            float4 w = Wq[e4 * 1024 + tid];
#pragma unroll
            for (int s = 0; s < NSEQ; ++s) {
                float4 hv = h4[s * 64 + e4];
                acc[s] = fmaf(w.x, hv.x, fmaf(w.y, hv.y, fmaf(w.z, hv.z, fmaf(w.w, hv.w, acc[s]))));
            }
        }
#pragma unroll
        for (int s = 0; s < NSEQ; ++s) aex[q][s][u] = acc[s];   // q == gate here
        __syncthreads();
        // update phase: thread (q,u) handles seqs s0,s1
        {
            float gi = sigf(aex[0][s0][u]);
            float gf = sigf(aex[1][s0][u]);
            float gg = tanhf(aex[2][s0][u]);
            float go = sigf(aex[3][s0][u]);
            c0 = fmaf(gf, c0, gi * gg);
            float hn = go * tanhf(c0);
            hs[s0][u] = hn;
            if (t == len0 - 1) h0dec[(wg * NSEQ + s0) * Hn + u] = hn;
        }
        {
            float gi = sigf(aex[0][s1][u]);
            float gf = sigf(aex[1][s1][u]);
            float gg = tanhf(aex[2][s1][u]);
            float go = sigf(aex[3][s1][u]);
            c1 = fmaf(gf, c1, gi * gg);
            float hn = go * tanhf(c1);
            hs[s1][u] = hn;
            if (t == len1 - 1) h0dec[(wg * NSEQ + s1) * Hn + u] = hn;
        }
        __syncthreads();
    }
}

// ---------------- decoder ----------------
__global__ __launch_bounds__(NT, 4) void dec_kernel(
    const float* __restrict__ Pt, const float4* __restrict__ Wq,
    const float4* __restrict__ Fq, const float* __restrict__ fcb,
    const float* __restrict__ h0dec, const int* __restrict__ sosp,
    float* __restrict__ out) {
    const int tid = threadIdx.x, wg = blockIdx.x;
    const int u = tid & 255;      // unit / vocab index depending on phase
    const int q = tid >> 8;       // gate (matmul) / seq-group (update,sum) / quarter (fc)
    __shared__ __align__(16) float hs[NSEQ][Hn];
    __shared__ __align__(16) float aex[4][NSEQ][Hn];   // gate exchange AND fc partials
    __shared__ int toks[NSEQ];
    __shared__ unsigned long long kbuf[NSEQ][4];

    const int s0 = 2 * q, s1 = 2 * q + 1;
    hs[s0][u] = h0dec[(wg * NSEQ + s0) * Hn + u];
    hs[s1][u] = h0dec[(wg * NSEQ + s1) * Hn + u];
    float c0 = 0.0f, c1 = 0.0f;
    if (tid < NSEQ) toks[tid] = sosp[0];
    const float bv = fcb[u];      // thread u <-> vocab v=u in sum phase
    __syncthreads();

    const float4* h4 = reinterpret_cast<const float4*>(&hs[0][0]);

    for (int t = 0; t < TPn; ++t) {
        // ---- gate matmul: thread=(g=q, u), 8 accumulators ----
        float acc[NSEQ];
#pragma unroll
        for (int s = 0; s < NSEQ; ++s) {
            int tk = toks[s];
            acc[s] = Pt[tk * 1024 + tid];
        }
#pragma unroll 8
        for (int e4 = 0; e4 < 64; ++e4) {
            float4 w = Wq[e4 * 1024 + tid];
#pragma unroll
            for (int s = 0; s < NSEQ; ++s) {
                float4 hv = h4[s * 64 + e4];
                acc[s] = fmaf(w.x, hv.x, fmaf(w.y, hv.y, fmaf(w.z, hv.z, fmaf(w.w, hv.w, acc[s]))));
            }
        }
#pragma unroll
        for (int s = 0; s < NSEQ; ++s) aex[q][s][u] = acc[s];
        __syncthreads();
        // ---- update: thread=(q,u) seqs {s0,s1} ----
        {
            float gi = sigf(aex[0][s0][u]);
            float gf = sigf(aex[1][s0][u]);
            float gg = tanhf(aex[2][s0][u]);
            float go = sigf(aex[3][s0][u]);
            c0 = fmaf(gf, c0, gi * gg);
            hs[s0][u] = go * tanhf(c0);
        }
        {
            float gi = sigf(aex[0][s1][u]);
            float gf = sigf(aex[1][s1][u]);
            float gg = tanhf(aex[2][s1][u]);
            float go = sigf(aex[3][s1][u]);
            c1 = fmaf(gf, c1, gi * gg);
            hs[s1][u] = go * tanhf(c1);
        }
        __syncthreads();
        // ---- fc partials: thread=(p=q, v=u) over h-quarter p ----
        float sc8[NSEQ];
#pragma unroll
        for (int s = 0; s < NSEQ; ++s) sc8[s] = 0.0f;
#pragma unroll 4
        for (int j = 0; j < 16; ++j) {
            int e4 = q * 16 + j;
            float4 w = Fq[e4 * 256 + u];
#pragma unroll
            for (int s = 0; s < NSEQ; ++s) {
                float4 hv = h4[s * 64 + e4];
                sc8[s] = fmaf(w.x, hv.x, fmaf(w.y, hv.y, fmaf(w.z, hv.z, fmaf(w.w, hv.w, sc8[s]))));
            }
        }
#pragma unroll
        for (int s = 0; s < NSEQ; ++s) aex[q][s][u] = sc8[s];   // reuse as partial buffer
        __syncthreads();
        // ---- sum + out + argmax: thread=(q, v=u) seqs {s0,s1} ----
        float scA = bv + aex[0][s0][u] + aex[1][s0][u] + aex[2][s0][u] + aex[3][s0][u];
        float scB = bv + aex[0][s1][u] + aex[1][s1][u] + aex[2][s1][u] + aex[3][s1][u];
        const long base = ((long)(wg * NSEQ) + 0) * TPn;
        out[((long)(wg * NSEQ + s0) * TPn + t) * Vn + u] = scA;
        out[((long)(wg * NSEQ + s1) * TPn + t) * Vn + u] = scB;
        (void)base;
        unsigned int fa = __float_as_uint(scA);
        fa = (fa & 0x80000000u) ? ~fa : (fa | 0x80000000u);
        unsigned int fb = __float_as_uint(scB);
        fb = (fb & 0x80000000u) ? ~fb : (fb | 0x80000000u);
        unsigned long long kA = ((unsigned long long)fa << 32) | (unsigned int)(Vn - 1 - u);
        unsigned long long kB = ((unsigned long long)fb << 32) | (unsigned int)(Vn - 1 - u);
#pragma unroll
        for (int off = 32; off > 0; off >>= 1) {
            unsigned long long oA = __shfl_xor(kA, off, 64);
            unsigned long long oB = __shfl_xor(kB, off, 64);
            if (oA > kA) kA = oA;
            if (oB > kB) kB = oB;
        }
        if ((tid & 63) == 0) {
            int qv = u >> 6;              // which v-quarter this wave covers
            kbuf[s0][qv] = kA;
            kbuf[s1][qv] = kB;
        }
        __syncthreads();
        if (tid < NSEQ) {
            unsigned long long k = kbuf[tid][0];
#pragma unroll
            for (int w = 1; w < 4; ++w)
                if (kbuf[tid][w] > k) k = kbuf[tid][w];
            toks[tid] = Vn - 1 - (int)(k & 0xffffffffu);
        }
        __syncthreads();
    }
}

// ---------------- launch ----------------
extern "C" void kernel_launch(void* const* d_in, const int* in_sizes, int n_in,
                              void* d_out, int out_size, void* d_ws, size_t ws_size,
                              hipStream_t stream) {
    const int*   phon = (const int*)d_in[0];
    const int*   lens = (const int*)d_in[1];
    const float* emb  = (const float*)d_in[2];
    const float* eWih = (const float*)d_in[3];
    const float* eWhh = (const float*)d_in[4];
    const float* ebih = (const float*)d_in[5];
    const float* ebhh = (const float*)d_in[6];
    const float* dWih = (const float*)d_in[7];
    const float* dWhh = (const float*)d_in[8];
    const float* dbih = (const float*)d_in[9];
    const float* dbhh = (const float*)d_in[10];
    const float* fcW  = (const float*)d_in[11];
    const float* fcb  = (const float*)d_in[12];
    const int*   sos  = (const int*)d_in[13];
    float* out = (float*)d_out;

    float*  Pt_e = (float*)d_ws;                  // 262144 floats = 1 MB
    float*  Pt_d = Pt_e + 262144;                 // 1 MB
    float4* Wq_e = (float4*)(Pt_d + 262144);      // 65536 float4 = 1 MB
    float4* Wq_d = Wq_e + 65536;                  // 1 MB
    float4* Fq   = Wq_d + 65536;                  // 16384 float4 = 256 KB
    float*  h0d  = (float*)(Fq + 16384);          // 524288 floats = 2 MB

    make_ptab<<<256, 1024, 0, stream>>>(Pt_e, emb, eWih, ebih, ebhh);
    make_ptab<<<256, 1024, 0, stream>>>(Pt_d, emb, dWih, dbih, dbhh);
    pack_whh<<<256, 256, 0, stream>>>(Wq_e, eWhh);
    pack_whh<<<256, 256, 0, stream>>>(Wq_d, dWhh);
    pack_fc<<<64, 256, 0, stream>>>(Fq, fcW);
    enc_kernel<<<NWG, NT, 0, stream>>>(Pt_e, Wq_e, phon, lens, h0d);
    dec_kernel<<<NWG, NT, 0, stream>>>(Pt_d, Wq_d, Fq, fcb, h0d, sos, out);
}